// Round 10
// baseline (229.552 us; speedup 1.0000x reference)
//
#include <hip/hip_runtime.h>

// GHM loss: focal (ch 0) + GHMR (ch 1..7), 3 scalar outputs.
//
// Ladder: 112 (grid-stride convoy) -> 70.7 (one-shot) -> 63.5 (4px/thread,
// no-clamp clean path). nt loads: refuted (L3 default retention best,
// FETCH 143MB). Model: dur ~= intercept + FETCH*0.29us/MB; intercept is
// wave-phase latency (load-burst -> wait -> compute-tail).
//
// This round: SOFTWARE-PIPELINED batches. 8 px/thread = 4 batches x 2 px,
// two named register buffers (static indexing), fully unrolled:
//   load B0; [load B1 | compute B0]; [load B2 | compute B1]; ...
// -> every wave keeps >=8 loads in flight while VALU runs; continuous
// memory demand instead of phase convoys.
//
// Pass 2: 22 parallel blocks (round-6 lesson: never single-block this).
// Pass 3: tiny finalize.
// Partials [quantity][block], NQ=22: q0..9 cum loss sums; q10 focal;
// q11 valid count; q12 zero (c_0 = 7*q11 derived); q13..21 cum counts.

#define NQ 22

typedef float vf4 __attribute__((ext_vector_type(4)));

__device__ __forceinline__ float wave_sum(float v) {
    v += __shfl_down(v, 32);
    v += __shfl_down(v, 16);
    v += __shfl_down(v, 8);
    v += __shfl_down(v, 4);
    v += __shfl_down(v, 2);
    v += __shfl_down(v, 1);
    return v;
}

__device__ __forceinline__ void ghm_epilogue(float lac[10], float facc,
                                             unsigned vcnt, const unsigned cnt[10],
                                             float* __restrict__ part, int nb) {
    const int tid = threadIdx.x;
    float vq[11] = { lac[0], lac[1], lac[2], lac[3], lac[4],
                     lac[5], lac[6], lac[7], lac[8], lac[9], facc };
#pragma unroll
    for (int q = 0; q < 11; ++q) vq[q] = wave_sum(vq[q]);

    __shared__ float sm[4][NQ];
    const int wave = tid >> 6, lane = tid & 63;
    if (lane == 0) {
#pragma unroll
        for (int q = 0; q < 11; ++q) sm[wave][q] = vq[q];
        sm[wave][11] = (float)vcnt;
        sm[wave][12] = 0.f;
#pragma unroll
        for (int b = 1; b < 10; ++b) sm[wave][12 + b] = (float)cnt[b];
    }
    __syncthreads();
    if (tid < NQ) {
        float v = sm[0][tid] + sm[1][tid] + sm[2][tid] + sm[3][tid];
        part[(size_t)tid * nb + blockIdx.x] = v;
    }
}

// process 2 pixels (4 f4 per array), accumulate
__device__ __forceinline__ void do2px(vf4 P0, vf4 P1, vf4 P2, vf4 P3,
                                      vf4 T0, vf4 T1, vf4 T2, vf4 T3,
                                      float lac[10], float& facc,
                                      unsigned cnt[10], unsigned& vcnt,
                                      const float C[10]) {
    constexpr float MU2 = 4.0e-4f;
    bool v1 = T0.x > 0.1f;
    bool v2 = T2.x > 0.1f;
    {
        float x  = P0.x;
        float xt = v1 ? x : 1.f - x;
        float at = v1 ? 0.25f : 0.75f;
        float om = 1.f - xt;
        facc += -at * om * om * __logf(xt + 1e-5f);
    }
    {
        float x  = P2.x;
        float xt = v2 ? x : 1.f - x;
        float at = v2 ? 0.25f : 0.75f;
        float om = 1.f - xt;
        facc += -at * om * om * __logf(xt + 1e-5f);
    }
    vcnt += (unsigned)__builtin_popcountll(__ballot(v1));
    vcnt += (unsigned)__builtin_popcountll(__ballot(v2));

    float pd[14] = {P0.y,P0.z,P0.w, P1.x,P1.y,P1.z,P1.w,
                    P2.y,P2.z,P2.w, P3.x,P3.y,P3.z,P3.w};
    float td[14] = {T0.y,T0.z,T0.w, T1.x,T1.y,T1.z,T1.w,
                    T2.y,T2.z,T2.w, T3.x,T3.y,T3.z,T3.w};
#pragma unroll
    for (int e = 0; e < 14; ++e) {
        bool  m  = (e < 7) ? v1 : v2;
        float d  = pd[e] - td[e];
        float d2 = d * d;
        float s  = __builtin_amdgcn_sqrtf(__builtin_fmaf(d, d, MU2));
        float loss = s - 0.02f;
        lac[0] += m ? loss : 0.f;       // bin 0 predicate == valid
        float d2m = m ? d2 : -1.f;
#pragma unroll
        for (int b = 1; b < 10; ++b) {
            bool pb = d2m >= C[b];
            lac[b] += pb ? loss : 0.f;
            cnt[b] += (unsigned)__builtin_popcountll(__ballot(pb));
        }
    }
}

// ---- clean pipelined path: n_pix % 2048 == 0, 8 px/thread, 4x2 batches ----
__global__ __launch_bounds__(256)
void ghm_pass1_p8(const vf4* __restrict__ preds, const vf4* __restrict__ tgts,
                  int n_pix, float* __restrict__ part, int nb) {
    const float C[10] = { -0.5f,
                          4.0404041e-6f, 1.6666667e-5f, 3.9560441e-5f,
                          7.6190476e-5f, 1.3333333e-4f, 2.2500000e-4f,
                          3.8431373e-4f, 7.1111111e-4f, 1.7052632e-3f };
    float lac[10];
#pragma unroll
    for (int b = 0; b < 10; ++b) lac[b] = 0.f;
    float facc = 0.f;
    unsigned int cnt[10] = {0,0,0,0,0,0,0,0,0,0};
    unsigned int vcnt = 0;

    const long g = (long)blockIdx.x * 256 + threadIdx.x;
    const vf4* pp = preds + 16 * g;   // 8 px = 16 float4 per array
    const vf4* tp = tgts  + 16 * g;

    vf4 pb0[4], tb0[4], pb1[4], tb1[4];
#pragma unroll
    for (int j = 0; j < 4; ++j) pb0[j] = pp[j];
#pragma unroll
    for (int j = 0; j < 4; ++j) tb0[j] = tp[j];

    // prefetch B1 | compute B0
#pragma unroll
    for (int j = 0; j < 4; ++j) pb1[j] = pp[4 + j];
#pragma unroll
    for (int j = 0; j < 4; ++j) tb1[j] = tp[4 + j];
    do2px(pb0[0],pb0[1],pb0[2],pb0[3], tb0[0],tb0[1],tb0[2],tb0[3],
          lac, facc, cnt, vcnt, C);

    // prefetch B2 | compute B1
#pragma unroll
    for (int j = 0; j < 4; ++j) pb0[j] = pp[8 + j];
#pragma unroll
    for (int j = 0; j < 4; ++j) tb0[j] = tp[8 + j];
    do2px(pb1[0],pb1[1],pb1[2],pb1[3], tb1[0],tb1[1],tb1[2],tb1[3],
          lac, facc, cnt, vcnt, C);

    // prefetch B3 | compute B2
#pragma unroll
    for (int j = 0; j < 4; ++j) pb1[j] = pp[12 + j];
#pragma unroll
    for (int j = 0; j < 4; ++j) tb1[j] = tp[12 + j];
    do2px(pb0[0],pb0[1],pb0[2],pb0[3], tb0[0],tb0[1],tb0[2],tb0[3],
          lac, facc, cnt, vcnt, C);

    // compute B3
    do2px(pb1[0],pb1[1],pb1[2],pb1[3], tb1[0],tb1[1],tb1[2],tb1[3],
          lac, facc, cnt, vcnt, C);

    ghm_epilogue(lac, facc, vcnt, cnt, part, nb);
}

// ---------------- generic path: 2 px/thread with clamps ----------------
__global__ __launch_bounds__(256)
void ghm_pass1_g2(const vf4* __restrict__ preds, const vf4* __restrict__ tgts,
                  int n_pix, float* __restrict__ part, int nb) {
    const float C[10] = { -0.5f,
                          4.0404041e-6f, 1.6666667e-5f, 3.9560441e-5f,
                          7.6190476e-5f, 1.3333333e-4f, 2.2500000e-4f,
                          3.8431373e-4f, 7.1111111e-4f, 1.7052632e-3f };
    float lac[10];
#pragma unroll
    for (int b = 0; b < 10; ++b) lac[b] = 0.f;
    float facc = 0.f;
    unsigned int cnt[10] = {0,0,0,0,0,0,0,0,0,0};
    unsigned int vcnt = 0;

    const int tid = threadIdx.x;
    const long total4 = 2L * (long)n_pix;

    for (long g = (long)blockIdx.x * 256 + tid; 2 * g < (long)n_pix;
         g += (long)gridDim.x * 256) {
        const long b4 = 4 * g;
        const bool in1 = (2 * g + 1) < (long)n_pix;
        const long i1 = (b4 + 1 < total4) ? b4 + 1 : total4 - 1;
        const long i2 = (b4 + 2 < total4) ? b4 + 2 : total4 - 1;
        const long i3 = (b4 + 3 < total4) ? b4 + 3 : total4 - 1;

        vf4 pA = preds[b4], pB = preds[i1], pC = preds[i2], pD = preds[i3];
        vf4 tA = tgts[b4],  tB = tgts[i1],  tC = tgts[i2],  tD = tgts[i3];

        bool v1 = tA.x > 0.1f;
        bool v2 = in1 && (tC.x > 0.1f);
        {
            float x = pA.x;
            float xt = v1 ? x : 1.f - x;
            float at = v1 ? 0.25f : 0.75f;
            float om = 1.f - xt;
            facc += -at * om * om * __logf(xt + 1e-5f);
        }
        {
            bool vv = tC.x > 0.1f;
            float x = pC.x;
            float xt = vv ? x : 1.f - x;
            float at = vv ? 0.25f : 0.75f;
            float om = 1.f - xt;
            float f = -at * om * om * __logf(xt + 1e-5f);
            facc += in1 ? f : 0.f;
        }
        vcnt += (unsigned)__builtin_popcountll(__ballot(v1));
        vcnt += (unsigned)__builtin_popcountll(__ballot(v2));

        float pd[14] = {pA.y,pA.z,pA.w, pB.x,pB.y,pB.z,pB.w,
                        pC.y,pC.z,pC.w, pD.x,pD.y,pD.z,pD.w};
        float td[14] = {tA.y,tA.z,tA.w, tB.x,tB.y,tB.z,tB.w,
                        tC.y,tC.z,tC.w, tD.x,tD.y,tD.z,tD.w};
        constexpr float MU2 = 4.0e-4f;
#pragma unroll
        for (int e = 0; e < 14; ++e) {
            bool m   = (e < 7) ? v1 : v2;
            float d  = pd[e] - td[e];
            float d2 = d * d;
            float s  = __builtin_amdgcn_sqrtf(__builtin_fmaf(d, d, MU2));
            float loss = s - 0.02f;
            lac[0] += m ? loss : 0.f;
            float d2m = m ? d2 : -1.f;
#pragma unroll
            for (int b = 1; b < 10; ++b) {
                bool pb = d2m >= C[b];
                lac[b] += pb ? loss : 0.f;
                cnt[b] += (unsigned)__builtin_popcountll(__ballot(pb));
            }
        }
    }
    ghm_epilogue(lac, facc, vcnt, cnt, part, nb);
}

// 22 parallel blocks: block q reduces part[q][0..nb) -> red[q]
__global__ __launch_bounds__(256)
void ghm_pass2(const float* __restrict__ part, int nb, float* __restrict__ red) {
    const int q = blockIdx.x;
    const int tid = threadIdx.x;
    float v = 0.f;
    for (int i = tid; i < nb; i += 256) v += part[(size_t)q * nb + i];
    v = wave_sum(v);
    __shared__ float wv[4];
    if ((tid & 63) == 0) wv[tid >> 6] = v;
    __syncthreads();
    if (tid == 0) red[q] = wv[0] + wv[1] + wv[2] + wv[3];
}

__global__ __launch_bounds__(64)
void ghm_pass3(const float* __restrict__ red, float* __restrict__ out,
               float inv_npix) {
    if (threadIdx.x == 0) {
        float tot = fmaxf(red[11], 1.f);
        float c0  = 7.f * red[11];
        float n = 0.f, sum = 0.f;
#pragma unroll
        for (int b = 0; b < 10; ++b) {
            float ccb = (b == 0) ? c0 : red[12 + b];
            float cb  = ccb    - (b < 9 ? red[12 + b + 1] : 0.f);
            float lb  = red[b] - (b < 9 ? red[b + 1]      : 0.f);
            if (cb > 0.f) {
                n += 1.f;
                sum += tot / fmaxf(0.3f * cb, 1e-30f) * lb;
            }
        }
        float reg = sum / fmaxf(n, 1.f) / tot;
        float cls = red[10] * inv_npix;
        out[0] = cls + reg;
        out[1] = reg;
        out[2] = cls;
    }
}

extern "C" void kernel_launch(void* const* d_in, const int* in_sizes, int n_in,
                              void* d_out, int out_size, void* d_ws, size_t ws_size,
                              hipStream_t stream) {
    const float* preds = (const float*)d_in[0];
    const float* tgts  = (const float*)d_in[1];
    const int n_pix = in_sizes[0] / 8;

    long cap = ((long)(ws_size / sizeof(float)) - NQ) / NQ;
    const bool clean = (n_pix % 2048) == 0 && (long)n_pix / 2048 <= cap;

    long want_nb = clean ? (long)n_pix / 2048 : ((long)n_pix + 511) / 512;
    long nb_l = want_nb < cap ? want_nb : cap;
    if (nb_l < 1) nb_l = 1;
    int nb = (int)nb_l;

    float* part = (float*)d_ws;
    float* red  = part + (size_t)NQ * nb;
    if (clean)
        ghm_pass1_p8<<<nb, 256, 0, stream>>>((const vf4*)preds, (const vf4*)tgts,
                                             n_pix, part, nb);
    else
        ghm_pass1_g2<<<nb, 256, 0, stream>>>((const vf4*)preds, (const vf4*)tgts,
                                             n_pix, part, nb);
    ghm_pass2<<<NQ, 256, 0, stream>>>(part, nb, red);
    ghm_pass3<<<1, 64, 0, stream>>>(red, (float*)d_out, 1.f / (float)n_pix);
}

// Round 11
// 76.521 us; speedup vs baseline: 2.9999x; 2.9999x over previous
//
#include <hip/hip_runtime.h>

// GHM loss: focal (ch 0) + GHMR (ch 1..7), 3 scalar outputs.
//
// Ladder: 112 (grid-stride convoy) -> 70.7 (one-shot) -> 63.5 (4px/thread
// clean path) -> [229 regression: 8px/thread = 256B/thread span -> VGPR 132,
// FETCH 360MB; REVERTED]. Lessons pinned:
//   - one-shot grid, no grid-stride convoy (round 4)
//   - 4 px/thread = one 128B line per thread per array (round 9/10)
//   - nt loads only hurt (round 7/8): default L3 retention (FETCH 141MB) is best
//   - never single-block the partial reduction (round 6)
// This round: pass2+pass3 FUSED via last-block finalize (device-scope
// atomics for cross-XCD visibility); counter zeroed per call by
// hipMemsetAsync (graph-capturable).
//
// Partials [quantity][block], NQ=22: q0..9 cum loss sums; q10 focal;
// q11 valid count; q12 zero (c_0 = 7*q11 derived); q13..21 cum counts b=1..9.

#define NQ 22

typedef float vf4 __attribute__((ext_vector_type(4)));

__device__ __forceinline__ float wave_sum(float v) {
    v += __shfl_down(v, 32);
    v += __shfl_down(v, 16);
    v += __shfl_down(v, 8);
    v += __shfl_down(v, 4);
    v += __shfl_down(v, 2);
    v += __shfl_down(v, 1);
    return v;
}

__device__ __forceinline__ void ghm_epilogue(float lac[10], float facc,
                                             unsigned vcnt, const unsigned cnt[10],
                                             float* __restrict__ part, int nb) {
    const int tid = threadIdx.x;
    float vq[11] = { lac[0], lac[1], lac[2], lac[3], lac[4],
                     lac[5], lac[6], lac[7], lac[8], lac[9], facc };
#pragma unroll
    for (int q = 0; q < 11; ++q) vq[q] = wave_sum(vq[q]);

    __shared__ float sm[4][NQ];
    const int wave = tid >> 6, lane = tid & 63;
    if (lane == 0) {
#pragma unroll
        for (int q = 0; q < 11; ++q) sm[wave][q] = vq[q];
        sm[wave][11] = (float)vcnt;
        sm[wave][12] = 0.f;
#pragma unroll
        for (int b = 1; b < 10; ++b) sm[wave][12 + b] = (float)cnt[b];
    }
    __syncthreads();
    if (tid < NQ) {
        float v = sm[0][tid] + sm[1][tid] + sm[2][tid] + sm[3][tid];
        part[(size_t)tid * nb + blockIdx.x] = v;
    }
}

// ---------------- clean path: n_pix % 1024 == 0, 4 px/thread ----------------
__global__ __launch_bounds__(256)
void ghm_pass1_c4(const vf4* __restrict__ preds, const vf4* __restrict__ tgts,
                  int n_pix, float* __restrict__ part, int nb) {
    constexpr float MU2 = 4.0e-4f;
    const float C[10] = { -0.5f,
                          4.0404041e-6f, 1.6666667e-5f, 3.9560441e-5f,
                          7.6190476e-5f, 1.3333333e-4f, 2.2500000e-4f,
                          3.8431373e-4f, 7.1111111e-4f, 1.7052632e-3f };

    float lac[10];
#pragma unroll
    for (int b = 0; b < 10; ++b) lac[b] = 0.f;
    float facc = 0.f;
    unsigned int cnt[10] = {0,0,0,0,0,0,0,0,0,0};
    unsigned int vcnt = 0;

    const int tid = threadIdx.x;

    for (long g = (long)blockIdx.x * 256 + tid; 4 * g < (long)n_pix;
         g += (long)gridDim.x * 256) {
        const long b4 = 8 * g;       // 4 pixels = 8 float4 = 128B per array
        vf4 p[8], t[8];
#pragma unroll
        for (int j = 0; j < 8; ++j) p[j] = preds[b4 + j];
#pragma unroll
        for (int j = 0; j < 8; ++j) t[j] = tgts[b4 + j];

        bool vld[4];
#pragma unroll
        for (int i = 0; i < 4; ++i) {
            vld[i] = t[2 * i].x > 0.1f;
            float x  = p[2 * i].x;
            float xt = vld[i] ? x : 1.f - x;
            float at = vld[i] ? 0.25f : 0.75f;
            float om = 1.f - xt;
            facc += -at * om * om * __logf(xt + 1e-5f);
            vcnt += (unsigned)__builtin_popcountll(__ballot(vld[i]));
        }

#pragma unroll
        for (int i = 0; i < 4; ++i) {
            float pd[7] = { p[2*i].y, p[2*i].z, p[2*i].w,
                            p[2*i+1].x, p[2*i+1].y, p[2*i+1].z, p[2*i+1].w };
            float td[7] = { t[2*i].y, t[2*i].z, t[2*i].w,
                            t[2*i+1].x, t[2*i+1].y, t[2*i+1].z, t[2*i+1].w };
            const bool m = vld[i];
#pragma unroll
            for (int e = 0; e < 7; ++e) {
                float d  = pd[e] - td[e];
                float d2 = d * d;
                float s  = __builtin_amdgcn_sqrtf(__builtin_fmaf(d, d, MU2));
                float loss = s - 0.02f;
                lac[0] += m ? loss : 0.f;        // bin 0 == valid
                float d2m = m ? d2 : -1.f;
#pragma unroll
                for (int b = 1; b < 10; ++b) {
                    bool pb = d2m >= C[b];
                    lac[b] += pb ? loss : 0.f;
                    cnt[b] += (unsigned)__builtin_popcountll(__ballot(pb));
                }
            }
        }
    }
    ghm_epilogue(lac, facc, vcnt, cnt, part, nb);
}

// ---------------- generic path: 2 px/thread with clamps ----------------
__global__ __launch_bounds__(256)
void ghm_pass1_g2(const vf4* __restrict__ preds, const vf4* __restrict__ tgts,
                  int n_pix, float* __restrict__ part, int nb) {
    constexpr float MU2 = 4.0e-4f;
    const float C[10] = { -0.5f,
                          4.0404041e-6f, 1.6666667e-5f, 3.9560441e-5f,
                          7.6190476e-5f, 1.3333333e-4f, 2.2500000e-4f,
                          3.8431373e-4f, 7.1111111e-4f, 1.7052632e-3f };

    float lac[10];
#pragma unroll
    for (int b = 0; b < 10; ++b) lac[b] = 0.f;
    float facc = 0.f;
    unsigned int cnt[10] = {0,0,0,0,0,0,0,0,0,0};
    unsigned int vcnt = 0;

    const int tid = threadIdx.x;
    const long total4 = 2L * (long)n_pix;

    for (long g = (long)blockIdx.x * 256 + tid; 2 * g < (long)n_pix;
         g += (long)gridDim.x * 256) {
        const long b4 = 4 * g;
        const bool in1 = (2 * g + 1) < (long)n_pix;
        const long i1 = (b4 + 1 < total4) ? b4 + 1 : total4 - 1;
        const long i2 = (b4 + 2 < total4) ? b4 + 2 : total4 - 1;
        const long i3 = (b4 + 3 < total4) ? b4 + 3 : total4 - 1;

        vf4 pA = preds[b4], pB = preds[i1], pC = preds[i2], pD = preds[i3];
        vf4 tA = tgts[b4],  tB = tgts[i1],  tC = tgts[i2],  tD = tgts[i3];

        bool v1 = tA.x > 0.1f;
        bool v2 = in1 && (tC.x > 0.1f);
        {
            float x = pA.x;
            float xt = v1 ? x : 1.f - x;
            float at = v1 ? 0.25f : 0.75f;
            float om = 1.f - xt;
            facc += -at * om * om * __logf(xt + 1e-5f);
        }
        {
            bool vv = tC.x > 0.1f;
            float x = pC.x;
            float xt = vv ? x : 1.f - x;
            float at = vv ? 0.25f : 0.75f;
            float om = 1.f - xt;
            float f = -at * om * om * __logf(xt + 1e-5f);
            facc += in1 ? f : 0.f;
        }
        vcnt += (unsigned)__builtin_popcountll(__ballot(v1));
        vcnt += (unsigned)__builtin_popcountll(__ballot(v2));

        float pd[14] = {pA.y,pA.z,pA.w, pB.x,pB.y,pB.z,pB.w,
                        pC.y,pC.z,pC.w, pD.x,pD.y,pD.z,pD.w};
        float td[14] = {tA.y,tA.z,tA.w, tB.x,tB.y,tB.z,tB.w,
                        tC.y,tC.z,tC.w, tD.x,tD.y,tD.z,tD.w};
#pragma unroll
        for (int e = 0; e < 14; ++e) {
            bool m   = (e < 7) ? v1 : v2;
            float d  = pd[e] - td[e];
            float d2 = d * d;
            float s  = __builtin_amdgcn_sqrtf(__builtin_fmaf(d, d, MU2));
            float loss = s - 0.02f;
            lac[0] += m ? loss : 0.f;
            float d2m = m ? d2 : -1.f;
#pragma unroll
            for (int b = 1; b < 10; ++b) {
                bool pb = d2m >= C[b];
                lac[b] += pb ? loss : 0.f;
                cnt[b] += (unsigned)__builtin_popcountll(__ballot(pb));
            }
        }
    }
    ghm_epilogue(lac, facc, vcnt, cnt, part, nb);
}

// Fused pass2+pass3: 22 parallel blocks; last-finishing block finalizes.
// Cross-XCD visibility via device-scope atomic RMWs on red[] (per-XCD L2s
// are not coherent for plain loads/stores — guide §6 G16).
__global__ __launch_bounds__(256)
void ghm_pass2f(const float* __restrict__ part, int nb,
                float* __restrict__ red, int* __restrict__ counter,
                float* __restrict__ out, float inv_npix) {
    const int q = blockIdx.x;
    const int tid = threadIdx.x;
    float v = 0.f;
    for (int i = tid; i < nb; i += 256) v += part[(size_t)q * nb + i];
    v = wave_sum(v);
    __shared__ float wv[4];
    if ((tid & 63) == 0) wv[tid >> 6] = v;
    __syncthreads();

    if (tid == 0) {
        float total = wv[0] + wv[1] + wv[2] + wv[3];
        atomicExch(&red[q], total);        // device-scope, coherent publish
        __threadfence();
        int old = atomicAdd(counter, 1);
        if (old == NQ - 1) {               // all 22 red[] published
            float r[NQ];
#pragma unroll
            for (int j = 0; j < NQ; ++j)
                r[j] = atomicAdd(&red[j], 0.f);   // coherent read
            float tot = fmaxf(r[11], 1.f);
            float c0  = 7.f * r[11];
            float n = 0.f, sum = 0.f;
#pragma unroll
            for (int b = 0; b < 10; ++b) {
                float ccb = (b == 0) ? c0 : r[12 + b];
                float cb  = ccb  - (b < 9 ? r[12 + b + 1] : 0.f);
                float lb  = r[b] - (b < 9 ? r[b + 1]      : 0.f);
                if (cb > 0.f) {
                    n += 1.f;
                    sum += tot / fmaxf(0.3f * cb, 1e-30f) * lb;
                }
            }
            float reg = sum / fmaxf(n, 1.f) / tot;
            float cls = r[10] * inv_npix;
            out[0] = cls + reg;
            out[1] = reg;
            out[2] = cls;
        }
    }
}

extern "C" void kernel_launch(void* const* d_in, const int* in_sizes, int n_in,
                              void* d_out, int out_size, void* d_ws, size_t ws_size,
                              hipStream_t stream) {
    const float* preds = (const float*)d_in[0];
    const float* tgts  = (const float*)d_in[1];
    const int n_pix = in_sizes[0] / 8;

    // ws layout: part[NQ][nb] | red[NQ] | counter(int)
    long cap = ((long)(ws_size / sizeof(float)) - NQ - 4) / NQ;
    const bool clean = (n_pix % 1024) == 0 && (long)n_pix / 1024 <= cap;
    long want_nb = clean ? (long)n_pix / 1024 : ((long)n_pix + 511) / 512;
    long nb_l = want_nb < cap ? want_nb : cap;
    if (nb_l < 1) nb_l = 1;
    int nb = (int)nb_l;

    float* part    = (float*)d_ws;
    float* red     = part + (size_t)NQ * nb;
    int*   counter = (int*)(red + NQ);

    hipMemsetAsync(counter, 0, sizeof(int), stream);   // graph-capturable

    if (clean)
        ghm_pass1_c4<<<nb, 256, 0, stream>>>((const vf4*)preds, (const vf4*)tgts,
                                             n_pix, part, nb);
    else
        ghm_pass1_g2<<<nb, 256, 0, stream>>>((const vf4*)preds, (const vf4*)tgts,
                                             n_pix, part, nb);
    ghm_pass2f<<<NQ, 256, 0, stream>>>(part, nb, red, counter,
                                       (float*)d_out, 1.f / (float)n_pix);
}

// Round 12
// 61.117 us; speedup vs baseline: 3.7559x; 1.2520x over previous
//
#include <hip/hip_runtime.h>

// GHM loss: focal (ch 0) + GHMR (ch 1..7), 3 scalar outputs.
//
// FINAL STRUCTURE (= round-9, best 63.5us, + float4 pass2 reads).
// Ladder/lessons:
//   112us grid-stride convoy -> 70.7 one-shot grid (round 4)
//   -> 63.5 with 4 px/thread clean path (round 9)
//   8 px/thread REFUTED (VGPR 132, FETCH 360MB: >128B/thread span is toxic)
//   nt loads REFUTED (kill default ~50% L3 retention; FETCH 141->267MB)
//   single-block tail REFUTED (232us: 1 CU latency-bound on 774KB)
//   atomic last-block fusion REFUTED (+13us: device-scope single-line
//     atomic convergence costs more than two extra small dispatches)
// Ceiling evidence: three different pass1 structures converge at
// ~5.4 TB/s delivered (HBM 2.7 + L3 2.7) => L2-miss/fabric fill wall.
//
// Pass 1 (clean, n_pix%1024==0): thread g owns pixels 4g..4g+3 = exactly
//   one 128B line per array. Bin test algebraic on d^2 vs
//   C_b = b^2*mu^2/(100-b^2); bin0 predicate == valid (c_0 = 7*q11,
//   derived in pass3); counts via ballot->popcll (scalar pipe).
// Pass 2: 22 parallel blocks, block q reduces part[q][*] -> red[q].
// Pass 3: 1 tiny block computes the 3 outputs.
//
// Partials [quantity][block], NQ=22: q0..9 cum loss sums; q10 focal;
// q11 valid count; q12 zero; q13..21 cum counts b=1..9.

#define NQ 22

typedef float vf4 __attribute__((ext_vector_type(4)));

__device__ __forceinline__ float wave_sum(float v) {
    v += __shfl_down(v, 32);
    v += __shfl_down(v, 16);
    v += __shfl_down(v, 8);
    v += __shfl_down(v, 4);
    v += __shfl_down(v, 2);
    v += __shfl_down(v, 1);
    return v;
}

__device__ __forceinline__ void ghm_epilogue(float lac[10], float facc,
                                             unsigned vcnt, const unsigned cnt[10],
                                             float* __restrict__ part, int nb) {
    const int tid = threadIdx.x;
    float vq[11] = { lac[0], lac[1], lac[2], lac[3], lac[4],
                     lac[5], lac[6], lac[7], lac[8], lac[9], facc };
#pragma unroll
    for (int q = 0; q < 11; ++q) vq[q] = wave_sum(vq[q]);

    __shared__ float sm[4][NQ];
    const int wave = tid >> 6, lane = tid & 63;
    if (lane == 0) {
#pragma unroll
        for (int q = 0; q < 11; ++q) sm[wave][q] = vq[q];
        sm[wave][11] = (float)vcnt;
        sm[wave][12] = 0.f;
#pragma unroll
        for (int b = 1; b < 10; ++b) sm[wave][12 + b] = (float)cnt[b];
    }
    __syncthreads();
    if (tid < NQ) {
        float v = sm[0][tid] + sm[1][tid] + sm[2][tid] + sm[3][tid];
        part[(size_t)tid * nb + blockIdx.x] = v;
    }
}

// ---------------- clean path: n_pix % 1024 == 0, 4 px/thread ----------------
__global__ __launch_bounds__(256)
void ghm_pass1_c4(const vf4* __restrict__ preds, const vf4* __restrict__ tgts,
                  int n_pix, float* __restrict__ part, int nb) {
    constexpr float MU2 = 4.0e-4f;
    const float C[10] = { -0.5f,
                          4.0404041e-6f, 1.6666667e-5f, 3.9560441e-5f,
                          7.6190476e-5f, 1.3333333e-4f, 2.2500000e-4f,
                          3.8431373e-4f, 7.1111111e-4f, 1.7052632e-3f };

    float lac[10];
#pragma unroll
    for (int b = 0; b < 10; ++b) lac[b] = 0.f;
    float facc = 0.f;
    unsigned int cnt[10] = {0,0,0,0,0,0,0,0,0,0};
    unsigned int vcnt = 0;

    const int tid = threadIdx.x;

    for (long g = (long)blockIdx.x * 256 + tid; 4 * g < (long)n_pix;
         g += (long)gridDim.x * 256) {
        const long b4 = 8 * g;       // 4 pixels = 8 float4 = 128B per array
        vf4 p[8], t[8];
#pragma unroll
        for (int j = 0; j < 8; ++j) p[j] = preds[b4 + j];
#pragma unroll
        for (int j = 0; j < 8; ++j) t[j] = tgts[b4 + j];

        bool vld[4];
#pragma unroll
        for (int i = 0; i < 4; ++i) {
            vld[i] = t[2 * i].x > 0.1f;
            float x  = p[2 * i].x;
            float xt = vld[i] ? x : 1.f - x;
            float at = vld[i] ? 0.25f : 0.75f;
            float om = 1.f - xt;
            facc += -at * om * om * __logf(xt + 1e-5f);
            vcnt += (unsigned)__builtin_popcountll(__ballot(vld[i]));
        }

#pragma unroll
        for (int i = 0; i < 4; ++i) {
            float pd[7] = { p[2*i].y, p[2*i].z, p[2*i].w,
                            p[2*i+1].x, p[2*i+1].y, p[2*i+1].z, p[2*i+1].w };
            float td[7] = { t[2*i].y, t[2*i].z, t[2*i].w,
                            t[2*i+1].x, t[2*i+1].y, t[2*i+1].z, t[2*i+1].w };
            const bool m = vld[i];
#pragma unroll
            for (int e = 0; e < 7; ++e) {
                float d  = pd[e] - td[e];
                float d2 = d * d;
                float s  = __builtin_amdgcn_sqrtf(__builtin_fmaf(d, d, MU2));
                float loss = s - 0.02f;
                lac[0] += m ? loss : 0.f;        // bin 0 == valid
                float d2m = m ? d2 : -1.f;
#pragma unroll
                for (int b = 1; b < 10; ++b) {
                    bool pb = d2m >= C[b];
                    lac[b] += pb ? loss : 0.f;
                    cnt[b] += (unsigned)__builtin_popcountll(__ballot(pb));
                }
            }
        }
    }
    ghm_epilogue(lac, facc, vcnt, cnt, part, nb);
}

// ---------------- generic path: 2 px/thread with clamps ----------------
__global__ __launch_bounds__(256)
void ghm_pass1_g2(const vf4* __restrict__ preds, const vf4* __restrict__ tgts,
                  int n_pix, float* __restrict__ part, int nb) {
    constexpr float MU2 = 4.0e-4f;
    const float C[10] = { -0.5f,
                          4.0404041e-6f, 1.6666667e-5f, 3.9560441e-5f,
                          7.6190476e-5f, 1.3333333e-4f, 2.2500000e-4f,
                          3.8431373e-4f, 7.1111111e-4f, 1.7052632e-3f };

    float lac[10];
#pragma unroll
    for (int b = 0; b < 10; ++b) lac[b] = 0.f;
    float facc = 0.f;
    unsigned int cnt[10] = {0,0,0,0,0,0,0,0,0,0};
    unsigned int vcnt = 0;

    const int tid = threadIdx.x;
    const long total4 = 2L * (long)n_pix;

    for (long g = (long)blockIdx.x * 256 + tid; 2 * g < (long)n_pix;
         g += (long)gridDim.x * 256) {
        const long b4 = 4 * g;
        const bool in1 = (2 * g + 1) < (long)n_pix;
        const long i1 = (b4 + 1 < total4) ? b4 + 1 : total4 - 1;
        const long i2 = (b4 + 2 < total4) ? b4 + 2 : total4 - 1;
        const long i3 = (b4 + 3 < total4) ? b4 + 3 : total4 - 1;

        vf4 pA = preds[b4], pB = preds[i1], pC = preds[i2], pD = preds[i3];
        vf4 tA = tgts[b4],  tB = tgts[i1],  tC = tgts[i2],  tD = tgts[i3];

        bool v1 = tA.x > 0.1f;
        bool v2 = in1 && (tC.x > 0.1f);
        {
            float x = pA.x;
            float xt = v1 ? x : 1.f - x;
            float at = v1 ? 0.25f : 0.75f;
            float om = 1.f - xt;
            facc += -at * om * om * __logf(xt + 1e-5f);
        }
        {
            bool vv = tC.x > 0.1f;
            float x = pC.x;
            float xt = vv ? x : 1.f - x;
            float at = vv ? 0.25f : 0.75f;
            float om = 1.f - xt;
            float f = -at * om * om * __logf(xt + 1e-5f);
            facc += in1 ? f : 0.f;
        }
        vcnt += (unsigned)__builtin_popcountll(__ballot(v1));
        vcnt += (unsigned)__builtin_popcountll(__ballot(v2));

        float pd[14] = {pA.y,pA.z,pA.w, pB.x,pB.y,pB.z,pB.w,
                        pC.y,pC.z,pC.w, pD.x,pD.y,pD.z,pD.w};
        float td[14] = {tA.y,tA.z,tA.w, tB.x,tB.y,tB.z,tB.w,
                        tC.y,tC.z,tC.w, tD.x,tD.y,tD.z,tD.w};
#pragma unroll
        for (int e = 0; e < 14; ++e) {
            bool m   = (e < 7) ? v1 : v2;
            float d  = pd[e] - td[e];
            float d2 = d * d;
            float s  = __builtin_amdgcn_sqrtf(__builtin_fmaf(d, d, MU2));
            float loss = s - 0.02f;
            lac[0] += m ? loss : 0.f;
            float d2m = m ? d2 : -1.f;
#pragma unroll
            for (int b = 1; b < 10; ++b) {
                bool pb = d2m >= C[b];
                lac[b] += pb ? loss : 0.f;
                cnt[b] += (unsigned)__builtin_popcountll(__ballot(pb));
            }
        }
    }
    ghm_epilogue(lac, facc, vcnt, cnt, part, nb);
}

// 22 parallel blocks: block q reduces part[q][0..nb) -> red[q]
__global__ __launch_bounds__(256)
void ghm_pass2(const float* __restrict__ part, int nb, float* __restrict__ red) {
    const int q = blockIdx.x;
    const int tid = threadIdx.x;
    float v = 0.f;
    const float* row = part + (size_t)q * nb;
    if ((nb & 3) == 0) {
        const vf4* row4 = (const vf4*)row;      // 16B-aligned when nb%4==0
        const int nb4 = nb >> 2;
        for (int i = tid; i < nb4; i += 256) {
            vf4 x = row4[i];
            v += x.x + x.y + x.z + x.w;
        }
    } else {
        for (int i = tid; i < nb; i += 256) v += row[i];
    }
    v = wave_sum(v);
    __shared__ float wv[4];
    if ((tid & 63) == 0) wv[tid >> 6] = v;
    __syncthreads();
    if (tid == 0) red[q] = wv[0] + wv[1] + wv[2] + wv[3];
}

__global__ __launch_bounds__(64)
void ghm_pass3(const float* __restrict__ red, float* __restrict__ out,
               float inv_npix) {
    if (threadIdx.x == 0) {
        float tot = fmaxf(red[11], 1.f);
        float c0  = 7.f * red[11];
        float n = 0.f, sum = 0.f;
#pragma unroll
        for (int b = 0; b < 10; ++b) {
            float ccb = (b == 0) ? c0 : red[12 + b];
            float cb  = ccb    - (b < 9 ? red[12 + b + 1] : 0.f);
            float lb  = red[b] - (b < 9 ? red[b + 1]      : 0.f);
            if (cb > 0.f) {
                n += 1.f;
                sum += tot / fmaxf(0.3f * cb, 1e-30f) * lb;
            }
        }
        float reg = sum / fmaxf(n, 1.f) / tot;
        float cls = red[10] * inv_npix;
        out[0] = cls + reg;
        out[1] = reg;
        out[2] = cls;
    }
}

extern "C" void kernel_launch(void* const* d_in, const int* in_sizes, int n_in,
                              void* d_out, int out_size, void* d_ws, size_t ws_size,
                              hipStream_t stream) {
    const float* preds = (const float*)d_in[0];
    const float* tgts  = (const float*)d_in[1];
    const int n_pix = in_sizes[0] / 8;

    long cap = ((long)(ws_size / sizeof(float)) - NQ) / NQ;
    const bool clean = (n_pix % 1024) == 0 && (long)n_pix / 1024 <= cap;
    long want_nb = clean ? (long)n_pix / 1024 : ((long)n_pix + 511) / 512;
    long nb_l = want_nb < cap ? want_nb : cap;
    if (nb_l < 1) nb_l = 1;
    int nb = (int)nb_l;

    float* part = (float*)d_ws;
    float* red  = part + (size_t)NQ * nb;
    if (clean)
        ghm_pass1_c4<<<nb, 256, 0, stream>>>((const vf4*)preds, (const vf4*)tgts,
                                             n_pix, part, nb);
    else
        ghm_pass1_g2<<<nb, 256, 0, stream>>>((const vf4*)preds, (const vf4*)tgts,
                                             n_pix, part, nb);
    ghm_pass2<<<NQ, 256, 0, stream>>>(part, nb, red);
    ghm_pass3<<<1, 64, 0, stream>>>(red, (float*)d_out, 1.f / (float)n_pix);
}